// Round 1
// baseline (166.613 us; speedup 1.0000x reference)
//
#include <hip/hip_runtime.h>

// MetricBiasUpdater: B_next = clip(alpha*B_prev - beta*relu(pairdist(H@W^T)), -10, 10)
// B=4, N=2048, D=1024, K(geom)=32. Output fp32 [4,2048,2048].

typedef __attribute__((ext_vector_type(8))) short short8;   // 8 bf16 (4 VGPRs)
typedef __attribute__((ext_vector_type(4))) float floatx4;  // MFMA acc

static __device__ __forceinline__ short bf16_bits(float f) {
    union { float f; unsigned int u; } v; v.f = f;
    unsigned int u = v.u;
    u += 0x7FFFu + ((u >> 16) & 1u);   // round-to-nearest-even
    return (short)(u >> 16);
}

// ---------------------------------------------------------------------------
// Kernel 1: G[row][k] = sum_d H[row][d] * W[k][d]  (rows = 8192 flat, k = 32)
// One block = one 16-row m-tile. 4 waves each take a K-quarter (256),
// 8 MFMA steps of K=32, two n-tiles (n=0..15, 16..31). LDS-reduce the 4
// partials, write G (fp32) and gsq (row sum of squares) to workspace.
// ---------------------------------------------------------------------------
__global__ __launch_bounds__(256) void k1_proj(const float* __restrict__ H,
                                               const float* __restrict__ W,
                                               float* __restrict__ G,
                                               float* __restrict__ Q) {
    const int blk  = blockIdx.x;        // 512 blocks x 16 rows
    const int t    = threadIdx.x;
    const int w    = t >> 6;            // wave id -> K quarter
    const int lane = t & 63;
    const int m    = lane & 15;         // A row within tile / B column n
    const int quad = lane >> 4;

    const float* hrow  = H + ((long)blk * 16 + m) * 1024;
    const float* wrow0 = W + (long)m * 1024;          // n-tile 0: n = m
    const float* wrow1 = W + (long)(m + 16) * 1024;   // n-tile 1: n = m+16

    const int kq = w * 256 + quad * 8;  // this lane's k base (A/B frag: k = quad*8 + j)

    floatx4 acc0 = {0.f, 0.f, 0.f, 0.f};
    floatx4 acc1 = {0.f, 0.f, 0.f, 0.f};

    float4 a0  = *(const float4*)(hrow  + kq);
    float4 a1  = *(const float4*)(hrow  + kq + 4);
    float4 b00 = *(const float4*)(wrow0 + kq);
    float4 b01 = *(const float4*)(wrow0 + kq + 4);
    float4 b10 = *(const float4*)(wrow1 + kq);
    float4 b11 = *(const float4*)(wrow1 + kq + 4);

    #pragma unroll
    for (int step = 0; step < 8; ++step) {
        float4 na0, na1, nb00, nb01, nb10, nb11;
        if (step < 7) {                 // prefetch next K-step while MFMA runs
            const int nk = kq + (step + 1) * 32;
            na0  = *(const float4*)(hrow  + nk);
            na1  = *(const float4*)(hrow  + nk + 4);
            nb00 = *(const float4*)(wrow0 + nk);
            nb01 = *(const float4*)(wrow0 + nk + 4);
            nb10 = *(const float4*)(wrow1 + nk);
            nb11 = *(const float4*)(wrow1 + nk + 4);
        }
        short8 af, bf0, bf1;
        af[0] = bf16_bits(a0.x);  af[1] = bf16_bits(a0.y);
        af[2] = bf16_bits(a0.z);  af[3] = bf16_bits(a0.w);
        af[4] = bf16_bits(a1.x);  af[5] = bf16_bits(a1.y);
        af[6] = bf16_bits(a1.z);  af[7] = bf16_bits(a1.w);
        bf0[0] = bf16_bits(b00.x); bf0[1] = bf16_bits(b00.y);
        bf0[2] = bf16_bits(b00.z); bf0[3] = bf16_bits(b00.w);
        bf0[4] = bf16_bits(b01.x); bf0[5] = bf16_bits(b01.y);
        bf0[6] = bf16_bits(b01.z); bf0[7] = bf16_bits(b01.w);
        bf1[0] = bf16_bits(b10.x); bf1[1] = bf16_bits(b10.y);
        bf1[2] = bf16_bits(b10.z); bf1[3] = bf16_bits(b10.w);
        bf1[4] = bf16_bits(b11.x); bf1[5] = bf16_bits(b11.y);
        bf1[6] = bf16_bits(b11.z); bf1[7] = bf16_bits(b11.w);

        acc0 = __builtin_amdgcn_mfma_f32_16x16x32_bf16(af, bf0, acc0, 0, 0, 0);
        acc1 = __builtin_amdgcn_mfma_f32_16x16x32_bf16(af, bf1, acc1, 0, 0, 0);

        if (step < 7) { a0 = na0; a1 = na1; b00 = nb00; b01 = nb01; b10 = nb10; b11 = nb11; }
    }

    // reduce K-quarter partials across the 4 waves.
    // C/D layout: col = lane&15, row = quad*4 + reg  (measured m89)
    __shared__ float red[4][16][32];
    #pragma unroll
    for (int r = 0; r < 4; ++r) {
        red[w][quad * 4 + r][m]      = acc0[r];
        red[w][quad * 4 + r][m + 16] = acc1[r];
    }
    __syncthreads();
    for (int e = t; e < 512; e += 256) {
        const int mm = e >> 5, nn = e & 31;
        float v = red[0][mm][nn] + red[1][mm][nn] + red[2][mm][nn] + red[3][mm][nn];
        G[(long)(blk * 16 + mm) * 32 + nn] = v;
        red[0][mm][nn] = v;
    }
    __syncthreads();
    if (t < 16) {
        float s = 0.f;
        #pragma unroll
        for (int nn = 0; nn < 32; ++nn) { const float v = red[0][t][nn]; s += v * v; }
        Q[blk * 16 + t] = s;
    }
}

// ---------------------------------------------------------------------------
// Kernel 2: out[b][i][j] = clip(alpha*Bp - beta*relu(q[i]+q[j]-2*G[i].G[j]))
// 128x128 tile per block, 8x8 per thread, XOR-swizzled G tiles in LDS.
// ---------------------------------------------------------------------------
__global__ __launch_bounds__(256) void k2_update(const float* __restrict__ Bp,
                                                 const float* __restrict__ G,
                                                 const float* __restrict__ Q,
                                                 const float* __restrict__ alphap,
                                                 const float* __restrict__ betap,
                                                 float* __restrict__ out) {
    __shared__ float4 sGi[128 * 8];   // [row][k-chunk], chunk position XOR-swizzled
    __shared__ float4 sGj[128 * 8];
    __shared__ float  sQi[128];
    __shared__ float  sQj[128];

    const int b  = blockIdx.z;
    const int i0 = blockIdx.y * 128;
    const int j0 = blockIdx.x * 128;
    const int t  = threadIdx.x;

    const float4* Gi4 = (const float4*)(G + ((long)b * 2048 + i0) * 32);
    const float4* Gj4 = (const float4*)(G + ((long)b * 2048 + j0) * 32);
    #pragma unroll
    for (int l = 0; l < 4; ++l) {
        const int f = t + l * 256;        // 1024 float4s = 128 rows x 8 chunks
        const int r = f >> 3, c = f & 7;
        const int cs = c ^ ((r >> 3) & 7);
        sGi[r * 8 + cs] = Gi4[f];
        sGj[r * 8 + cs] = Gj4[f];
    }
    if (t < 128) sQi[t] = Q[b * 2048 + i0 + t];
    else         sQj[t - 128] = Q[b * 2048 + j0 + (t - 128)];
    __syncthreads();

    const int tx = t & 15;   // j-group: j = j0 + tx*8 + jj
    const int ty = t >> 4;   // i-group: i = i0 + ty*8 + ii

    float acc[8][8];
    #pragma unroll
    for (int ii = 0; ii < 8; ++ii)
        #pragma unroll
        for (int jj = 0; jj < 8; ++jj) acc[ii][jj] = 0.f;

    #pragma unroll
    for (int c = 0; c < 8; ++c) {
        float4 gi[8], gj[8];
        #pragma unroll
        for (int u = 0; u < 8; ++u) {
            const int ri = ty * 8 + u;
            gi[u] = sGi[ri * 8 + (c ^ ((ri >> 3) & 7))];
            const int rj = tx * 8 + u;
            gj[u] = sGj[rj * 8 + (c ^ ((rj >> 3) & 7))];
        }
        #pragma unroll
        for (int ii = 0; ii < 8; ++ii)
            #pragma unroll
            for (int jj = 0; jj < 8; ++jj)
                acc[ii][jj] += gi[ii].x * gj[jj].x + gi[ii].y * gj[jj].y +
                               gi[ii].z * gj[jj].z + gi[ii].w * gj[jj].w;
    }

    const float alpha = alphap[0];
    const float beta  = betap[0];

    #pragma unroll
    for (int ii = 0; ii < 8; ++ii) {
        const int i = i0 + ty * 8 + ii;
        const long rowoff = ((long)b * 2048 + i) * 2048 + j0;
        const float4* bp = (const float4*)(Bp + rowoff);
        float4*       op = (float4*)(out + rowoff);
        const float qi = sQi[ty * 8 + ii];
        #pragma unroll
        for (int g = 0; g < 2; ++g) {
            const float4 bv = bp[tx * 2 + g];
            float4 ov;
            {
                const int jj = g * 4 + 0;
                float d = qi + sQj[tx * 8 + jj] - 2.f * acc[ii][jj];
                d = fmaxf(d, 0.f);
                ov.x = fminf(fmaxf(alpha * bv.x - beta * d, -10.f), 10.f);
            }
            {
                const int jj = g * 4 + 1;
                float d = qi + sQj[tx * 8 + jj] - 2.f * acc[ii][jj];
                d = fmaxf(d, 0.f);
                ov.y = fminf(fmaxf(alpha * bv.y - beta * d, -10.f), 10.f);
            }
            {
                const int jj = g * 4 + 2;
                float d = qi + sQj[tx * 8 + jj] - 2.f * acc[ii][jj];
                d = fmaxf(d, 0.f);
                ov.z = fminf(fmaxf(alpha * bv.z - beta * d, -10.f), 10.f);
            }
            {
                const int jj = g * 4 + 3;
                float d = qi + sQj[tx * 8 + jj] - 2.f * acc[ii][jj];
                d = fmaxf(d, 0.f);
                ov.w = fminf(fmaxf(alpha * bv.w - beta * d, -10.f), 10.f);
            }
            op[tx * 2 + g] = ov;
        }
    }
}

extern "C" void kernel_launch(void* const* d_in, const int* in_sizes, int n_in,
                              void* d_out, int out_size, void* d_ws, size_t ws_size,
                              hipStream_t stream) {
    const float* H     = (const float*)d_in[0];   // [4,2048,1024]
    const float* Bp    = (const float*)d_in[1];   // [4,2048,2048]
    const float* W     = (const float*)d_in[2];   // [32,1024]
    const float* alpha = (const float*)d_in[3];
    const float* beta  = (const float*)d_in[4];
    float* out = (float*)d_out;

    float* G = (float*)d_ws;          // [8192][32] fp32 = 1 MB
    float* Q = G + 8192 * 32;         // [8192] row sums of squares

    k1_proj<<<512, 256, 0, stream>>>(H, W, G, Q);

    dim3 g2(16, 16, 4);               // j-tiles, i-tiles, batch
    k2_update<<<g2, 256, 0, stream>>>(Bp, G, Q, alpha, beta, out);
}